// Round 4
// baseline (7642.098 us; speedup 1.0000x reference)
//
#include <hip/hip_runtime.h>
#include <math.h>

#define BB 32
#define TT 512
#define DD 512
#define UU 512
#define G3 1536   // 3*U
#define CHUNK 64  // time steps per xg chunk

__device__ __forceinline__ float hsig(float x) {
    return fminf(fmaxf(fmaf(0.2f, x, 0.5f), 0.0f), 1.0f);
}

// LLC-coherent accessors (sc1): bypass the non-cross-XCD-coherent L2s.
__device__ __forceinline__ float llc_load(const float* p) {
    return __hip_atomic_load(p, __ATOMIC_RELAXED, __HIP_MEMORY_SCOPE_AGENT);
}
__device__ __forceinline__ void llc_store(float* p, float v) {
    __hip_atomic_store(p, v, __ATOMIC_RELAXED, __HIP_MEMORY_SCOPE_AGENT);
}
__device__ __forceinline__ unsigned llc_load_u(const unsigned* p) {
    return __hip_atomic_load(p, __ATOMIC_RELAXED, __HIP_MEMORY_SCOPE_AGENT);
}
__device__ __forceinline__ void llc_store_u(unsigned* p, unsigned v) {
    __hip_atomic_store(p, v, __ATOMIC_RELAXED, __HIP_MEMORY_SCOPE_AGENT);
}

// ---------------------------------------------------------------------------
// Kernel A: x_gates chunk GEMM (proven rounds 2-4, unchanged).
// ---------------------------------------------------------------------------
__global__ __launch_bounds__(256) void xg_gemm(
    const float* __restrict__ x,
    const float* __restrict__ Wf, const float* __restrict__ bf,
    const float* __restrict__ Wb, const float* __restrict__ bb,
    float* __restrict__ xgc, int t0)
{
    const int dir = blockIdx.z;
    const int n0  = blockIdx.x * 64;
    const int m0  = blockIdx.y * 128;
    const float* W    = dir ? Wb : Wf;
    const float* bias = dir ? bb : bf;

    __shared__ float As[16][132];
    __shared__ float Bs[16][64];

    const int tid = threadIdx.x;
    const int tx = tid & 15, ty = tid >> 4;

    float acc[8][4];
    #pragma unroll
    for (int i = 0; i < 8; ++i)
        #pragma unroll
        for (int q = 0; q < 4; ++q) acc[i][q] = 0.f;

    const int lmr = tid >> 2;
    const int ak4 = (tid & 3) * 4;
    const float* arow0;
    const float* arow1;
    {
        int m = m0 + lmr;
        int b = m & 31, i = m >> 5;
        int tp = dir ? (TT - 1 - t0 - i) : (t0 + i);
        arow0 = x + ((size_t)b * TT + tp) * DD;
        m = m0 + lmr + 64;
        b = m & 31; i = m >> 5;
        tp = dir ? (TT - 1 - t0 - i) : (t0 + i);
        arow1 = x + ((size_t)b * TT + tp) * DD;
    }
    const float* bsrc = W + (size_t)(tid >> 4) * G3 + n0 + (tid & 15) * 4;

    for (int k0 = 0; k0 < DD; k0 += 16) {
        float4 a0 = *(const float4*)(arow0 + k0 + ak4);
        float4 a1 = *(const float4*)(arow1 + k0 + ak4);
        float4 bv = *(const float4*)(bsrc + (size_t)k0 * G3);
        __syncthreads();
        As[ak4 + 0][lmr] = a0.x;  As[ak4 + 1][lmr] = a0.y;
        As[ak4 + 2][lmr] = a0.z;  As[ak4 + 3][lmr] = a0.w;
        As[ak4 + 0][lmr + 64] = a1.x;  As[ak4 + 1][lmr + 64] = a1.y;
        As[ak4 + 2][lmr + 64] = a1.z;  As[ak4 + 3][lmr + 64] = a1.w;
        *(float4*)&Bs[tid >> 4][(tid & 15) * 4] = bv;
        __syncthreads();
        #pragma unroll
        for (int kk = 0; kk < 16; ++kk) {
            float4 b4 = *(const float4*)&Bs[kk][tx * 4];
            #pragma unroll
            for (int i = 0; i < 8; ++i) {
                float a = As[kk][ty * 8 + i];
                acc[i][0] = fmaf(a, b4.x, acc[i][0]);
                acc[i][1] = fmaf(a, b4.y, acc[i][1]);
                acc[i][2] = fmaf(a, b4.z, acc[i][2]);
                acc[i][3] = fmaf(a, b4.w, acc[i][3]);
            }
        }
    }

    float4 bv = *(const float4*)(bias + n0 + tx * 4);
    #pragma unroll
    for (int i = 0; i < 8; ++i) {
        int m = m0 + ty * 8 + i;
        float4 o;
        o.x = acc[i][0] + bv.x;  o.y = acc[i][1] + bv.y;
        o.z = acc[i][2] + bv.z;  o.w = acc[i][3] + bv.w;
        *(float4*)(xgc + ((size_t)dir * (CHUNK * BB) + m) * G3 + n0 + tx * 4) = o;
    }
}

// ---------------------------------------------------------------------------
// Flag-array group barrier.  WG w stores `target` into its own slot; wave 0's
// lanes poll all 32 slots.  Entry __syncthreads drains each wave's vmcnt, so
// prior sc1 data stores are globally visible before the flag store.
// Round-3 hardening: release fence before the flag store, acquire fence after
// the poll — forbids the compiler from hoisting subsequent (batched) staging
// loads above the relaxed spin loop, which is the round-0/round-2 race.
// ---------------------------------------------------------------------------
__device__ __forceinline__ void flag_barrier(unsigned* flags, int w,
                                             unsigned target) {
    __syncthreads();
    if (threadIdx.x < 64) {
        if (threadIdx.x == 0) {
            __builtin_amdgcn_fence(__ATOMIC_RELEASE, "agent");
            llc_store_u(flags + w, target);
        }
        const unsigned* slot = flags + (threadIdx.x & 31);
        while (llc_load_u(slot) < target)
            __builtin_amdgcn_s_sleep(1);
        __builtin_amdgcn_fence(__ATOMIC_ACQUIRE, "agent");
    }
    __syncthreads();
}

// ---------------------------------------------------------------------------
// Batched LLC staging: 8 rows of 512 floats, thread tid takes column tid of
// every row.  All 8 loads issue inside ONE volatile asm block (single
// vmcnt(0) drain = one LLC latency instead of eight), and volatile asm
// cannot be hoisted above the flag poll/barrier.  Values land fully inside
// the block, then plain ds_writes (no rule-18 hazard).
// ---------------------------------------------------------------------------
#define WSTRIDE 516
#define NWCOLS 48
#define P1S 264   // phase-1 part stride (mod 32 == 8)
#define P2S 132   // phase-2 part stride (mod 32 == 4)
#define LDS_FLOATS (NWCOLS * WSTRIDE + 8 * WSTRIDE + 9216 + 640)

__device__ __forceinline__ void llc_stage8(const float* __restrict__ src,
                                           float* __restrict__ hp, int tid) {
    const float* p0 = src + tid;           // rows 0,1 (offset:2048 = +512 fl)
    const float* p1 = src + tid + 1024;    // rows 2,3
    const float* p2 = src + tid + 2048;    // rows 4,5
    const float* p3 = src + tid + 3072;    // rows 6,7
    float a0, a1, a2, a3, a4, a5, a6, a7;
    asm volatile(
        "global_load_dword %0, %8, off sc0 sc1\n\t"
        "global_load_dword %1, %8, off offset:2048 sc0 sc1\n\t"
        "global_load_dword %2, %9, off sc0 sc1\n\t"
        "global_load_dword %3, %9, off offset:2048 sc0 sc1\n\t"
        "global_load_dword %4, %10, off sc0 sc1\n\t"
        "global_load_dword %5, %10, off offset:2048 sc0 sc1\n\t"
        "global_load_dword %6, %11, off sc0 sc1\n\t"
        "global_load_dword %7, %11, off offset:2048 sc0 sc1\n\t"
        "s_waitcnt vmcnt(0)"
        : "=&v"(a0), "=&v"(a1), "=&v"(a2), "=&v"(a3),
          "=&v"(a4), "=&v"(a5), "=&v"(a6), "=&v"(a7)
        : "v"(p0), "v"(p1), "v"(p2), "v"(p3)
        : "memory");
    hp[tid]               = a0;
    hp[WSTRIDE + tid]     = a1;
    hp[2 * WSTRIDE + tid] = a2;
    hp[3 * WSTRIDE + tid] = a3;
    hp[4 * WSTRIDE + tid] = a4;
    hp[5 * WSTRIDE + tid] = a5;
    hp[6 * WSTRIDE + tid] = a6;
    hp[7 * WSTRIDE + tid] = a7;
}

__global__ __launch_bounds__(512, 1) void gru_chunk(
    const float* __restrict__ Uf, const float* __restrict__ Ub,
    const float* __restrict__ xgc,
    float* __restrict__ hbuf, float* __restrict__ rhbuf,
    unsigned* __restrict__ bars, float* __restrict__ out, int c)
{
    extern __shared__ float lds[];
    float* Wl   = lds;                        // 48 cols * 516
    float* hp   = Wl + NWCOLS * WSTRIDE;      // 8 rows * 516 (h, then rh)
    float* part = hp + 8 * WSTRIDE;           // 9216 (transposed partials)
    float* zloc = part + 9216;                // 8*16
    float* hloc = zloc + 128;                 // 8*16
    float* xg_l = hloc + 128;                 // 384: xz/xr (256) + xh (128)

    const int tid = threadIdx.x;
    const int g   = blockIdx.x >> 5;   // group 0..7
    const int w   = blockIdx.x & 31;   // WG within group
    const int dir = g >> 2;
    const int b0  = (g & 3) * 8;

    unsigned* flags = bars + g * 32;
    const unsigned base = (unsigned)(c * 128);

    const float* U = dir ? Ub : Uf;
    const int j0 = w * 16;             // owned j-range for z, r, cand

    // ---- stage weights: cc 0..15 = Uz[:,j0+..], 16..31 = Ur, 32..47 = Uh ----
    for (int q = tid; q < 512 * 12; q += 512) {
        int k  = q & 511;
        int jj = q >> 9;                  // 0..11 (float4 spans)
        int gate = jj >> 2;               // 0=z,1=r,2=cand
        int off  = (jj & 3) * 4;
        int n  = gate * 512 + j0 + off;
        int cc = gate * 16 + off;
        float4 v = *(const float4*)(U + (size_t)k * G3 + n);
        float* wc = Wl + (size_t)cc * WSTRIDE + k;
        wc[0]           = v.x;
        wc[WSTRIDE]     = v.y;
        wc[2 * WSTRIDE] = v.z;
        wc[3 * WSTRIDE] = v.w;
    }
    __syncthreads();

    float* hg_h  = hbuf  + ((size_t)dir * 32 + b0) * 512;
    float* hg_rh = rhbuf + ((size_t)dir * 32 + b0) * 512;

    for (int i = 0; i < CHUNK; ++i) {
        const int t = c * CHUNK + i;

        // ---- issue xg prefetch (plain loads; drain with staging vmcnt) ----
        float xgv = 0.f;
        if (tid < 384) {
            size_t off;
            if (tid < 256) {
                off = (((size_t)dir * CHUNK + i) * BB + (b0 + (tid >> 5))) * G3
                    + (size_t)(((tid & 31) >> 4) * 512) + j0 + (tid & 15);
            } else {
                int o2 = tid - 256;
                off = (((size_t)dir * CHUNK + i) * BB + (b0 + (o2 >> 4))) * G3
                    + 1024 + j0 + (o2 & 15);
            }
            xgv = xgc[off];
        }

        // ---- stage h into hp (batched asm sc1 loads) ----
        llc_stage8(hg_h, hp, tid);
        if (tid < 384) xg_l[tid] = xgv;
        __syncthreads();

        // ---- phase 1 dots: 32 cols (16 z + 16 r) x 8 batches, K=512 ----
        {
            const int cslot = tid & 7;
            const int bslot = (tid >> 3) & 1;
            const int ks    = tid >> 4;      // 0..31
            const int kb    = ks * 16;
            const float* wp = Wl + (size_t)cslot * WSTRIDE + kb;
            const float* hq = hp + (size_t)(bslot * 4) * WSTRIDE + kb;
            float acc[4][4];
            #pragma unroll
            for (int a = 0; a < 4; ++a)
                #pragma unroll
                for (int b = 0; b < 4; ++b) acc[a][b] = 0.f;
            #pragma unroll
            for (int kk = 0; kk < 16; kk += 4) {
                float4 wv[4], hv[4];
                #pragma unroll
                for (int ci = 0; ci < 4; ++ci)
                    wv[ci] = *(const float4*)(wp + (size_t)ci * (8 * WSTRIDE) + kk);
                #pragma unroll
                for (int bi = 0; bi < 4; ++bi)
                    hv[bi] = *(const float4*)(hq + (size_t)bi * WSTRIDE + kk);
                #pragma unroll
                for (int ci = 0; ci < 4; ++ci)
                    #pragma unroll
                    for (int bi = 0; bi < 4; ++bi) {
                        acc[ci][bi] = fmaf(wv[ci].x, hv[bi].x, acc[ci][bi]);
                        acc[ci][bi] = fmaf(wv[ci].y, hv[bi].y, acc[ci][bi]);
                        acc[ci][bi] = fmaf(wv[ci].z, hv[bi].z, acc[ci][bi]);
                        acc[ci][bi] = fmaf(wv[ci].w, hv[bi].w, acc[ci][bi]);
                    }
            }
            #pragma unroll
            for (int ci = 0; ci < 4; ++ci)
                #pragma unroll
                for (int bi = 0; bi < 4; ++bi) {
                    int o = (bslot * 4 + bi) * 32 + cslot + 8 * ci;
                    part[(size_t)ks * P1S + o] = acc[ci][bi];
                }
        }
        __syncthreads();

        // ---- phase 1 reduce + epilogue: z->LDS, rh->LLC, h_old->LDS ----
        if (tid < 256) {
            const int o = tid;
            float s0 = 0.f, s1 = 0.f, s2 = 0.f, s3 = 0.f;
            #pragma unroll
            for (int ks = 0; ks < 32; ks += 4) {
                s0 += part[(size_t)(ks + 0) * P1S + o];
                s1 += part[(size_t)(ks + 1) * P1S + o];
                s2 += part[(size_t)(ks + 2) * P1S + o];
                s3 += part[(size_t)(ks + 3) * P1S + o];
            }
            float s = ((s0 + s1) + (s2 + s3)) + xg_l[o];
            const int b_l = o >> 5, cc = o & 31;
            const int gate = cc >> 4;              // 0=z, 1=r
            const int jl = cc & 15;
            const int j = j0 + jl;
            float gv = hsig(s);
            const float hval = hp[(size_t)b_l * WSTRIDE + j];
            if (gate == 0) {
                zloc[b_l * 16 + jl] = gv;
                hloc[b_l * 16 + jl] = hval;
            } else {
                llc_store(hg_rh + (size_t)b_l * 512 + j, gv * hval);
            }
        }
        flag_barrier(flags, w, base + (unsigned)(i * 2) + 1u);

        // ---- stage rh into hp (batched asm sc1 loads) ----
        llc_stage8(hg_rh, hp, tid);
        __syncthreads();

        // ---- phase 2 dots: 16 cand cols x 8 batches, K=512 ----
        {
            const int cslot = tid & 3;
            const int bslot = (tid >> 2) & 1;
            const int ks    = tid >> 3;      // 0..63
            const int kb    = ks * 8;
            const float* wp = Wl + (size_t)(32 + cslot) * WSTRIDE + kb;
            const float* hq = hp + (size_t)(bslot * 4) * WSTRIDE + kb;
            float acc[4][4];
            #pragma unroll
            for (int a = 0; a < 4; ++a)
                #pragma unroll
                for (int b = 0; b < 4; ++b) acc[a][b] = 0.f;
            #pragma unroll
            for (int kk = 0; kk < 8; kk += 4) {
                float4 wv[4], hv[4];
                #pragma unroll
                for (int ci = 0; ci < 4; ++ci)
                    wv[ci] = *(const float4*)(wp + (size_t)ci * (4 * WSTRIDE) + kk);
                #pragma unroll
                for (int bi = 0; bi < 4; ++bi)
                    hv[bi] = *(const float4*)(hq + (size_t)bi * WSTRIDE + kk);
                #pragma unroll
                for (int ci = 0; ci < 4; ++ci)
                    #pragma unroll
                    for (int bi = 0; bi < 4; ++bi) {
                        acc[ci][bi] = fmaf(wv[ci].x, hv[bi].x, acc[ci][bi]);
                        acc[ci][bi] = fmaf(wv[ci].y, hv[bi].y, acc[ci][bi]);
                        acc[ci][bi] = fmaf(wv[ci].z, hv[bi].z, acc[ci][bi]);
                        acc[ci][bi] = fmaf(wv[ci].w, hv[bi].w, acc[ci][bi]);
                    }
            }
            #pragma unroll
            for (int ci = 0; ci < 4; ++ci)
                #pragma unroll
                for (int bi = 0; bi < 4; ++bi) {
                    int o = (bslot * 4 + bi) * 16 + cslot + 4 * ci;
                    part[(size_t)ks * P2S + o] = acc[ci][bi];
                }
        }
        __syncthreads();

        // ---- phase 2 reduce + h update (z, h_old from LDS) ----
        if (tid < 128) {
            const int o = tid;
            float s0 = 0.f, s1 = 0.f, s2 = 0.f, s3 = 0.f;
            #pragma unroll
            for (int ks = 0; ks < 64; ks += 4) {
                s0 += part[(size_t)(ks + 0) * P2S + o];
                s1 += part[(size_t)(ks + 1) * P2S + o];
                s2 += part[(size_t)(ks + 2) * P2S + o];
                s3 += part[(size_t)(ks + 3) * P2S + o];
            }
            float s = ((s0 + s1) + (s2 + s3)) + xg_l[256 + o];
            const int b_l = o >> 4, jl = o & 15;
            const int j = j0 + jl;
            float cand = tanhf(s);
            float z = zloc[b_l * 16 + jl];
            float h = hloc[b_l * 16 + jl];
            float hn = fmaf(z, h - cand, cand);   // z*h + (1-z)*cand
            llc_store(hg_h + (size_t)b_l * 512 + j, hn);
            out[((size_t)(b0 + b_l) * TT + t) * (2 * UU) + (size_t)dir * UU + j] = hn;
        }
        flag_barrier(flags, w, base + (unsigned)(i * 2) + 2u);
    }
}

extern "C" void kernel_launch(void* const* d_in, const int* in_sizes, int n_in,
                              void* d_out, int out_size, void* d_ws, size_t ws_size,
                              hipStream_t stream) {
    const float* x  = (const float*)d_in[0];
    const float* Wf = (const float*)d_in[1];
    const float* Uf = (const float*)d_in[2];
    const float* bf = (const float*)d_in[3];
    const float* Wb = (const float*)d_in[4];
    const float* Ub = (const float*)d_in[5];
    const float* bb = (const float*)d_in[6];
    float* out = (float*)d_out;

    // ws: h[2][32][512], rh[2][32][512] (256 KB) + flags (1 KB) + xgc (~25 MB)
    float* hbuf  = (float*)d_ws;
    float* rhbuf = hbuf + 2 * BB * UU;
    unsigned* bars = (unsigned*)(rhbuf + 2 * BB * UU);
    float* xgc   = (float*)(bars + 512);

    hipMemsetAsync(d_ws, 0, (size_t)(2 * 2 * BB * UU) * sizeof(float) + 2048, stream);

    static_assert(LDS_FLOATS * 4 <= 160 * 1024, "LDS overflow");
    hipFuncSetAttribute((const void*)gru_chunk,
                        hipFuncAttributeMaxDynamicSharedMemorySize,
                        LDS_FLOATS * 4);

    for (int c = 0; c < TT / CHUNK; ++c) {
        xg_gemm<<<dim3(24, 16, 2), 256, 0, stream>>>(
            x, Wf, bf, Wb, bb, xgc, c * CHUNK);
        gru_chunk<<<dim3(256), dim3(512), LDS_FLOATS * 4, stream>>>(
            Uf, Ub, xgc, hbuf, rhbuf, bars, out, c);
    }
}

// Round 7
// 4073.330 us; speedup vs baseline: 1.8761x; 1.8761x over previous
//
#include <hip/hip_runtime.h>
#include <math.h>

#define BB 32
#define TT 512
#define DD 512
#define UU 512
#define G3 1536   // 3*U
#define CHUNK 64  // time steps per xg chunk

__device__ __forceinline__ float hsig(float x) {
    return fminf(fmaxf(fmaf(0.2f, x, 0.5f), 0.0f), 1.0f);
}

// Single 8B LLC-coherent store: (tag<<32)|float_bits.  Atomicity of the
// naturally-aligned 64-bit store is the ONLY hardware guarantee the exchange
// protocol relies on — no cross-address ordering anywhere (the round-0/2/4
// races were all cross-address ordering: flag visible at LLC before data).
__device__ __forceinline__ void llc_store_u64(unsigned long long* p,
                                              unsigned long long v) {
    __hip_atomic_store(p, v, __ATOMIC_RELAXED, __HIP_MEMORY_SCOPE_AGENT);
}
__device__ __forceinline__ unsigned long long pack_tv(unsigned tag, float v) {
    return ((unsigned long long)tag << 32) |
           (unsigned long long)__float_as_uint(v);
}

// ---------------------------------------------------------------------------
// Kernel A: x_gates chunk GEMM (proven, unchanged).
// ---------------------------------------------------------------------------
__global__ __launch_bounds__(256) void xg_gemm(
    const float* __restrict__ x,
    const float* __restrict__ Wf, const float* __restrict__ bf,
    const float* __restrict__ Wb, const float* __restrict__ bb,
    float* __restrict__ xgc, int t0)
{
    const int dir = blockIdx.z;
    const int n0  = blockIdx.x * 64;
    const int m0  = blockIdx.y * 128;
    const float* W    = dir ? Wb : Wf;
    const float* bias = dir ? bb : bf;

    __shared__ float As[16][132];
    __shared__ float Bs[16][64];

    const int tid = threadIdx.x;
    const int tx = tid & 15, ty = tid >> 4;

    float acc[8][4];
    #pragma unroll
    for (int i = 0; i < 8; ++i)
        #pragma unroll
        for (int q = 0; q < 4; ++q) acc[i][q] = 0.f;

    const int lmr = tid >> 2;
    const int ak4 = (tid & 3) * 4;
    const float* arow0;
    const float* arow1;
    {
        int m = m0 + lmr;
        int b = m & 31, i = m >> 5;
        int tp = dir ? (TT - 1 - t0 - i) : (t0 + i);
        arow0 = x + ((size_t)b * TT + tp) * DD;
        m = m0 + lmr + 64;
        b = m & 31; i = m >> 5;
        tp = dir ? (TT - 1 - t0 - i) : (t0 + i);
        arow1 = x + ((size_t)b * TT + tp) * DD;
    }
    const float* bsrc = W + (size_t)(tid >> 4) * G3 + n0 + (tid & 15) * 4;

    for (int k0 = 0; k0 < DD; k0 += 16) {
        float4 a0 = *(const float4*)(arow0 + k0 + ak4);
        float4 a1 = *(const float4*)(arow1 + k0 + ak4);
        float4 bv = *(const float4*)(bsrc + (size_t)k0 * G3);
        __syncthreads();
        As[ak4 + 0][lmr] = a0.x;  As[ak4 + 1][lmr] = a0.y;
        As[ak4 + 2][lmr] = a0.z;  As[ak4 + 3][lmr] = a0.w;
        As[ak4 + 0][lmr + 64] = a1.x;  As[ak4 + 1][lmr + 64] = a1.y;
        As[ak4 + 2][lmr + 64] = a1.z;  As[ak4 + 3][lmr + 64] = a1.w;
        *(float4*)&Bs[tid >> 4][(tid & 15) * 4] = bv;
        __syncthreads();
        #pragma unroll
        for (int kk = 0; kk < 16; ++kk) {
            float4 b4 = *(const float4*)&Bs[kk][tx * 4];
            #pragma unroll
            for (int i = 0; i < 8; ++i) {
                float a = As[kk][ty * 8 + i];
                acc[i][0] = fmaf(a, b4.x, acc[i][0]);
                acc[i][1] = fmaf(a, b4.y, acc[i][1]);
                acc[i][2] = fmaf(a, b4.z, acc[i][2]);
                acc[i][3] = fmaf(a, b4.w, acc[i][3]);
            }
        }
    }

    float4 bv = *(const float4*)(bias + n0 + tx * 4);
    #pragma unroll
    for (int i = 0; i < 8; ++i) {
        int m = m0 + ty * 8 + i;
        float4 o;
        o.x = acc[i][0] + bv.x;  o.y = acc[i][1] + bv.y;
        o.z = acc[i][2] + bv.z;  o.w = acc[i][3] + bv.w;
        *(float4*)(xgc + ((size_t)dir * (CHUNK * BB) + m) * G3 + n0 + tx * 4) = o;
    }
}

// ---------------------------------------------------------------------------
// Tagged staging: 8 rows x 512 cols of (tag,value) pairs; thread tid takes
// column tid of every row.  Batched 8x dwordx2 in ONE asm block (single LLC
// latency); per-thread retry until every tag matches `exp`.  Each element is
// self-validating, so no flag, no barrier, no cross-address ordering.
// Bounded spin (2^18 ~= 4 orders of magnitude above legitimate inter-WG
// skew; all 256 WGs co-resident at 151KB LDS/CU): a protocol flaw then
// surfaces as a wrong-value test failure instead of a GPU hang that is
// indistinguishable from the harness's container-infra failures.
// ---------------------------------------------------------------------------
#define WSTRIDE 516
#define NWCOLS 48
#define P1S 264   // phase-1 part stride (mod 32 == 8)
#define P2S 132   // phase-2 part stride (mod 32 == 4)
#define LDS_FLOATS (NWCOLS * WSTRIDE + 8 * WSTRIDE + 9216 + 640)

__device__ __forceinline__ void stage_tagged(
    const unsigned long long* __restrict__ src,
    float* __restrict__ hp, int tid, unsigned exp)
{
    const unsigned long long* p0 = src + tid;
    const unsigned long long* p1 = src + tid + 512;
    const unsigned long long* p2 = src + tid + 1024;
    const unsigned long long* p3 = src + tid + 1536;
    const unsigned long long* p4 = src + tid + 2048;
    const unsigned long long* p5 = src + tid + 2560;
    const unsigned long long* p6 = src + tid + 3072;
    const unsigned long long* p7 = src + tid + 3584;
    unsigned long long d0, d1, d2, d3, d4, d5, d6, d7;
    for (int spin = 0;; ++spin) {
        asm volatile(
            "global_load_dwordx2 %0, %8, off sc0 sc1\n\t"
            "global_load_dwordx2 %1, %9, off sc0 sc1\n\t"
            "global_load_dwordx2 %2, %10, off sc0 sc1\n\t"
            "global_load_dwordx2 %3, %11, off sc0 sc1\n\t"
            "global_load_dwordx2 %4, %12, off sc0 sc1\n\t"
            "global_load_dwordx2 %5, %13, off sc0 sc1\n\t"
            "global_load_dwordx2 %6, %14, off sc0 sc1\n\t"
            "global_load_dwordx2 %7, %15, off sc0 sc1\n\t"
            "s_waitcnt vmcnt(0)"
            : "=&v"(d0), "=&v"(d1), "=&v"(d2), "=&v"(d3),
              "=&v"(d4), "=&v"(d5), "=&v"(d6), "=&v"(d7)
            : "v"(p0), "v"(p1), "v"(p2), "v"(p3),
              "v"(p4), "v"(p5), "v"(p6), "v"(p7)
            : "memory");
        unsigned bad = (((unsigned)(d0 >> 32)) ^ exp) |
                       (((unsigned)(d1 >> 32)) ^ exp) |
                       (((unsigned)(d2 >> 32)) ^ exp) |
                       (((unsigned)(d3 >> 32)) ^ exp) |
                       (((unsigned)(d4 >> 32)) ^ exp) |
                       (((unsigned)(d5 >> 32)) ^ exp) |
                       (((unsigned)(d6 >> 32)) ^ exp) |
                       (((unsigned)(d7 >> 32)) ^ exp);
        if (bad == 0u || spin > (1 << 18)) break;
        __builtin_amdgcn_s_sleep(1);
    }
    hp[tid]               = __uint_as_float((unsigned)d0);
    hp[WSTRIDE + tid]     = __uint_as_float((unsigned)d1);
    hp[2 * WSTRIDE + tid] = __uint_as_float((unsigned)d2);
    hp[3 * WSTRIDE + tid] = __uint_as_float((unsigned)d3);
    hp[4 * WSTRIDE + tid] = __uint_as_float((unsigned)d4);
    hp[5 * WSTRIDE + tid] = __uint_as_float((unsigned)d5);
    hp[6 * WSTRIDE + tid] = __uint_as_float((unsigned)d6);
    hp[7 * WSTRIDE + tid] = __uint_as_float((unsigned)d7);
}

// ---------------------------------------------------------------------------
// Persistent chunk kernel.  Group = 32 WGs (dir x batch-quad).  WG w owns
// j-range [w*16,(w+1)*16) for z, r, cand.  Exchange via tagged ping-pong:
//   h(t):  parity t&1, tag t+1   (read at step t+1 from parity t&1, exp t+1)
//   rh(t): parity t&1, tag t+1   (read at step t   from parity t&1, exp t+1)
// Initial h(-1): parity 1, tag 0 == memset zeros.  Writing step t+2 data
// requires (via the rh(t+1)->h(t+1) dependency chain) every WG to have
// finished reading step t data, so 2-deep rotation is overwrite-safe with
// no barrier at all: the full-width staging read IS the inter-WG barrier.
// ---------------------------------------------------------------------------
__global__ __launch_bounds__(512, 1) void gru_chunk(
    const float* __restrict__ Uf, const float* __restrict__ Ub,
    const float* __restrict__ xgc,
    unsigned long long* __restrict__ hbuf,
    unsigned long long* __restrict__ rhbuf,
    float* __restrict__ out, int c)
{
    extern __shared__ float lds[];
    float* Wl   = lds;                        // 48 cols * 516
    float* hp   = Wl + NWCOLS * WSTRIDE;      // 8 rows * 516 (h, then rh)
    float* part = hp + 8 * WSTRIDE;           // 9216 (transposed partials)
    float* zloc = part + 9216;                // 8*16
    float* hloc = zloc + 128;                 // 8*16
    float* xg_l = hloc + 128;                 // 384: xz/xr (256) + xh (128)

    const int tid = threadIdx.x;
    const int g   = blockIdx.x >> 5;   // group 0..7
    const int w   = blockIdx.x & 31;   // WG within group
    const int dir = g >> 2;
    const int b0  = (g & 3) * 8;

    const float* U = dir ? Ub : Uf;
    const int j0 = w * 16;             // owned j-range for z, r, cand

    unsigned long long* hg_h[2];
    unsigned long long* hg_rh[2];
    hg_h[0]  = hbuf  + ((size_t)(0 * 2 + dir) * 32 + b0) * 512;
    hg_h[1]  = hbuf  + ((size_t)(1 * 2 + dir) * 32 + b0) * 512;
    hg_rh[0] = rhbuf + ((size_t)(0 * 2 + dir) * 32 + b0) * 512;
    hg_rh[1] = rhbuf + ((size_t)(1 * 2 + dir) * 32 + b0) * 512;

    // ---- stage weights: cc 0..15 = Uz[:,j0+..], 16..31 = Ur, 32..47 = Uh ----
    for (int q = tid; q < 512 * 12; q += 512) {
        int k  = q & 511;
        int jj = q >> 9;                  // 0..11 (float4 spans)
        int gate = jj >> 2;               // 0=z,1=r,2=cand
        int off  = (jj & 3) * 4;
        int n  = gate * 512 + j0 + off;
        int cc = gate * 16 + off;
        float4 v = *(const float4*)(U + (size_t)k * G3 + n);
        float* wc = Wl + (size_t)cc * WSTRIDE + k;
        wc[0]           = v.x;
        wc[WSTRIDE]     = v.y;
        wc[2 * WSTRIDE] = v.z;
        wc[3 * WSTRIDE] = v.w;
    }
    __syncthreads();

    for (int i = 0; i < CHUNK; ++i) {
        const int t = c * CHUNK + i;
        const int par = t & 1;
        const unsigned tag_next = (unsigned)(t + 1);

        // ---- issue xg prefetch (plain loads; drain with staging vmcnt) ----
        float xgv = 0.f;
        if (tid < 384) {
            size_t off;
            if (tid < 256) {
                off = (((size_t)dir * CHUNK + i) * BB + (b0 + (tid >> 5))) * G3
                    + (size_t)(((tid & 31) >> 4) * 512) + j0 + (tid & 15);
            } else {
                int o2 = tid - 256;
                off = (((size_t)dir * CHUNK + i) * BB + (b0 + (o2 >> 4))) * G3
                    + 1024 + j0 + (o2 & 15);
            }
            xgv = xgc[off];
        }

        // ---- stage h(t-1): parity par^1, expect tag t ----
        stage_tagged(hg_h[par ^ 1], hp, tid, (unsigned)t);
        if (tid < 384) xg_l[tid] = xgv;
        __syncthreads();

        // ---- phase 1 dots: 32 cols (16 z + 16 r) x 8 batches, K=512 ----
        {
            const int cslot = tid & 7;
            const int bslot = (tid >> 3) & 1;
            const int ks    = tid >> 4;      // 0..31
            const int kb    = ks * 16;
            const float* wp = Wl + (size_t)cslot * WSTRIDE + kb;
            const float* hq = hp + (size_t)(bslot * 4) * WSTRIDE + kb;
            float acc[4][4];
            #pragma unroll
            for (int a = 0; a < 4; ++a)
                #pragma unroll
                for (int b = 0; b < 4; ++b) acc[a][b] = 0.f;
            #pragma unroll
            for (int kk = 0; kk < 16; kk += 4) {
                float4 wv[4], hv[4];
                #pragma unroll
                for (int ci = 0; ci < 4; ++ci)
                    wv[ci] = *(const float4*)(wp + (size_t)ci * (8 * WSTRIDE) + kk);
                #pragma unroll
                for (int bi = 0; bi < 4; ++bi)
                    hv[bi] = *(const float4*)(hq + (size_t)bi * WSTRIDE + kk);
                #pragma unroll
                for (int ci = 0; ci < 4; ++ci)
                    #pragma unroll
                    for (int bi = 0; bi < 4; ++bi) {
                        acc[ci][bi] = fmaf(wv[ci].x, hv[bi].x, acc[ci][bi]);
                        acc[ci][bi] = fmaf(wv[ci].y, hv[bi].y, acc[ci][bi]);
                        acc[ci][bi] = fmaf(wv[ci].z, hv[bi].z, acc[ci][bi]);
                        acc[ci][bi] = fmaf(wv[ci].w, hv[bi].w, acc[ci][bi]);
                    }
            }
            #pragma unroll
            for (int ci = 0; ci < 4; ++ci)
                #pragma unroll
                for (int bi = 0; bi < 4; ++bi) {
                    int o = (bslot * 4 + bi) * 32 + cslot + 8 * ci;
                    part[(size_t)ks * P1S + o] = acc[ci][bi];
                }
        }
        __syncthreads();

        // ---- phase 1 reduce + epilogue: z->LDS, rh->(tag,val) LLC ----
        if (tid < 256) {
            const int o = tid;
            float s0 = 0.f, s1 = 0.f, s2 = 0.f, s3 = 0.f;
            #pragma unroll
            for (int ks = 0; ks < 32; ks += 4) {
                s0 += part[(size_t)(ks + 0) * P1S + o];
                s1 += part[(size_t)(ks + 1) * P1S + o];
                s2 += part[(size_t)(ks + 2) * P1S + o];
                s3 += part[(size_t)(ks + 3) * P1S + o];
            }
            float s = ((s0 + s1) + (s2 + s3)) + xg_l[o];
            const int b_l = o >> 5, cc = o & 31;
            const int gate = cc >> 4;              // 0=z, 1=r
            const int jl = cc & 15;
            const int j = j0 + jl;
            float gv = hsig(s);
            const float hval = hp[(size_t)b_l * WSTRIDE + j];
            if (gate == 0) {
                zloc[b_l * 16 + jl] = gv;
                hloc[b_l * 16 + jl] = hval;
            } else {
                llc_store_u64(hg_rh[par] + (size_t)b_l * 512 + j,
                              pack_tv(tag_next, gv * hval));
            }
        }
        __syncthreads();   // hp/part reads done before restage/overwrite

        // ---- stage rh(t): parity par, expect tag t+1 ----
        stage_tagged(hg_rh[par], hp, tid, tag_next);
        __syncthreads();

        // ---- phase 2 dots: 16 cand cols x 8 batches, K=512 ----
        {
            const int cslot = tid & 3;
            const int bslot = (tid >> 2) & 1;
            const int ks    = tid >> 3;      // 0..63
            const int kb    = ks * 8;
            const float* wp = Wl + (size_t)(32 + cslot) * WSTRIDE + kb;
            const float* hq = hp + (size_t)(bslot * 4) * WSTRIDE + kb;
            float acc[4][4];
            #pragma unroll
            for (int a = 0; a < 4; ++a)
                #pragma unroll
                for (int b = 0; b < 4; ++b) acc[a][b] = 0.f;
            #pragma unroll
            for (int kk = 0; kk < 8; kk += 4) {
                float4 wv[4], hv[4];
                #pragma unroll
                for (int ci = 0; ci < 4; ++ci)
                    wv[ci] = *(const float4*)(wp + (size_t)ci * (4 * WSTRIDE) + kk);
                #pragma unroll
                for (int bi = 0; bi < 4; ++bi)
                    hv[bi] = *(const float4*)(hq + (size_t)bi * WSTRIDE + kk);
                #pragma unroll
                for (int ci = 0; ci < 4; ++ci)
                    #pragma unroll
                    for (int bi = 0; bi < 4; ++bi) {
                        acc[ci][bi] = fmaf(wv[ci].x, hv[bi].x, acc[ci][bi]);
                        acc[ci][bi] = fmaf(wv[ci].y, hv[bi].y, acc[ci][bi]);
                        acc[ci][bi] = fmaf(wv[ci].z, hv[bi].z, acc[ci][bi]);
                        acc[ci][bi] = fmaf(wv[ci].w, hv[bi].w, acc[ci][bi]);
                    }
            }
            #pragma unroll
            for (int ci = 0; ci < 4; ++ci)
                #pragma unroll
                for (int bi = 0; bi < 4; ++bi) {
                    int o = (bslot * 4 + bi) * 16 + cslot + 4 * ci;
                    part[(size_t)ks * P2S + o] = acc[ci][bi];
                }
        }
        __syncthreads();

        // ---- phase 2 reduce + h update (z, h_old from LDS) ----
        if (tid < 128) {
            const int o = tid;
            float s0 = 0.f, s1 = 0.f, s2 = 0.f, s3 = 0.f;
            #pragma unroll
            for (int ks = 0; ks < 64; ks += 4) {
                s0 += part[(size_t)(ks + 0) * P2S + o];
                s1 += part[(size_t)(ks + 1) * P2S + o];
                s2 += part[(size_t)(ks + 2) * P2S + o];
                s3 += part[(size_t)(ks + 3) * P2S + o];
            }
            float s = ((s0 + s1) + (s2 + s3)) + xg_l[256 + o];
            const int b_l = o >> 4, jl = o & 15;
            const int j = j0 + jl;
            float cand = tanhf(s);
            float z = zloc[b_l * 16 + jl];
            float h = hloc[b_l * 16 + jl];
            float hn = fmaf(z, h - cand, cand);   // z*h + (1-z)*cand
            llc_store_u64(hg_h[par] + (size_t)b_l * 512 + j,
                          pack_tv(tag_next, hn));
            out[((size_t)(b0 + b_l) * TT + t) * (2 * UU) + (size_t)dir * UU + j] = hn;
        }
        __syncthreads();   // xg_l/zloc/hloc/part reads done before next step
    }
}

extern "C" void kernel_launch(void* const* d_in, const int* in_sizes, int n_in,
                              void* d_out, int out_size, void* d_ws, size_t ws_size,
                              hipStream_t stream) {
    const float* x  = (const float*)d_in[0];
    const float* Wf = (const float*)d_in[1];
    const float* Uf = (const float*)d_in[2];
    const float* bf = (const float*)d_in[3];
    const float* Wb = (const float*)d_in[4];
    const float* Ub = (const float*)d_in[5];
    const float* bb = (const float*)d_in[6];
    float* out = (float*)d_out;

    // ws: tagged ping-pong h[2][2][32][512] u64 (512KB) + rh same (512KB)
    //     + xgc (~25 MB)
    unsigned long long* hbuf  = (unsigned long long*)d_ws;
    unsigned long long* rhbuf = hbuf + (size_t)4 * BB * UU;   // 65536 u64
    float* xgc = (float*)(rhbuf + (size_t)4 * BB * UU);

    hipMemsetAsync(d_ws, 0, (size_t)8 * 4 * BB * UU * 2, stream);  // 1 MiB

    static_assert(LDS_FLOATS * 4 <= 160 * 1024, "LDS overflow");
    hipFuncSetAttribute((const void*)gru_chunk,
                        hipFuncAttributeMaxDynamicSharedMemorySize,
                        LDS_FLOATS * 4);

    for (int c = 0; c < TT / CHUNK; ++c) {
        xg_gemm<<<dim3(24, 16, 2), 256, 0, stream>>>(
            x, Wf, bf, Wb, bb, xgc, c * CHUNK);
        gru_chunk<<<dim3(256), dim3(512), LDS_FLOATS * 4, stream>>>(
            Uf, Ub, xgc, hbuf, rhbuf, out, c);
    }
}

// Round 8
// 3980.885 us; speedup vs baseline: 1.9197x; 1.0232x over previous
//
#include <hip/hip_runtime.h>
#include <math.h>

#define BB 32
#define TT 512
#define DD 512
#define UU 512
#define G3 1536   // 3*U
#define CHUNK 64  // time steps per xg chunk

__device__ __forceinline__ float hsig(float x) {
    return fminf(fmaxf(fmaf(0.2f, x, 0.5f), 0.0f), 1.0f);
}

// Single 8B LLC-coherent store: (tag<<32)|float_bits.  Atomicity of the
// naturally-aligned 64-bit store is the ONLY hardware guarantee the exchange
// protocol relies on — no cross-address ordering anywhere.
__device__ __forceinline__ void llc_store_u64(unsigned long long* p,
                                              unsigned long long v) {
    __hip_atomic_store(p, v, __ATOMIC_RELAXED, __HIP_MEMORY_SCOPE_AGENT);
}
__device__ __forceinline__ unsigned long long pack_tv(unsigned tag, float v) {
    return ((unsigned long long)tag << 32) |
           (unsigned long long)__float_as_uint(v);
}

// ---------------------------------------------------------------------------
// Kernel A: x_gates chunk GEMM (proven, unchanged).
// ---------------------------------------------------------------------------
__global__ __launch_bounds__(256) void xg_gemm(
    const float* __restrict__ x,
    const float* __restrict__ Wf, const float* __restrict__ bf,
    const float* __restrict__ Wb, const float* __restrict__ bb,
    float* __restrict__ xgc, int t0)
{
    const int dir = blockIdx.z;
    const int n0  = blockIdx.x * 64;
    const int m0  = blockIdx.y * 128;
    const float* W    = dir ? Wb : Wf;
    const float* bias = dir ? bb : bf;

    __shared__ float As[16][132];
    __shared__ float Bs[16][64];

    const int tid = threadIdx.x;
    const int tx = tid & 15, ty = tid >> 4;

    float acc[8][4];
    #pragma unroll
    for (int i = 0; i < 8; ++i)
        #pragma unroll
        for (int q = 0; q < 4; ++q) acc[i][q] = 0.f;

    const int lmr = tid >> 2;
    const int ak4 = (tid & 3) * 4;
    const float* arow0;
    const float* arow1;
    {
        int m = m0 + lmr;
        int b = m & 31, i = m >> 5;
        int tp = dir ? (TT - 1 - t0 - i) : (t0 + i);
        arow0 = x + ((size_t)b * TT + tp) * DD;
        m = m0 + lmr + 64;
        b = m & 31; i = m >> 5;
        tp = dir ? (TT - 1 - t0 - i) : (t0 + i);
        arow1 = x + ((size_t)b * TT + tp) * DD;
    }
    const float* bsrc = W + (size_t)(tid >> 4) * G3 + n0 + (tid & 15) * 4;

    for (int k0 = 0; k0 < DD; k0 += 16) {
        float4 a0 = *(const float4*)(arow0 + k0 + ak4);
        float4 a1 = *(const float4*)(arow1 + k0 + ak4);
        float4 bv = *(const float4*)(bsrc + (size_t)k0 * G3);
        __syncthreads();
        As[ak4 + 0][lmr] = a0.x;  As[ak4 + 1][lmr] = a0.y;
        As[ak4 + 2][lmr] = a0.z;  As[ak4 + 3][lmr] = a0.w;
        As[ak4 + 0][lmr + 64] = a1.x;  As[ak4 + 1][lmr + 64] = a1.y;
        As[ak4 + 2][lmr + 64] = a1.z;  As[ak4 + 3][lmr + 64] = a1.w;
        *(float4*)&Bs[tid >> 4][(tid & 15) * 4] = bv;
        __syncthreads();
        #pragma unroll
        for (int kk = 0; kk < 16; ++kk) {
            float4 b4 = *(const float4*)&Bs[kk][tx * 4];
            #pragma unroll
            for (int i = 0; i < 8; ++i) {
                float a = As[kk][ty * 8 + i];
                acc[i][0] = fmaf(a, b4.x, acc[i][0]);
                acc[i][1] = fmaf(a, b4.y, acc[i][1]);
                acc[i][2] = fmaf(a, b4.z, acc[i][2]);
                acc[i][3] = fmaf(a, b4.w, acc[i][3]);
            }
        }
    }

    float4 bv = *(const float4*)(bias + n0 + tx * 4);
    #pragma unroll
    for (int i = 0; i < 8; ++i) {
        int m = m0 + ty * 8 + i;
        float4 o;
        o.x = acc[i][0] + bv.x;  o.y = acc[i][1] + bv.y;
        o.z = acc[i][2] + bv.z;  o.w = acc[i][3] + bv.w;
        *(float4*)(xgc + ((size_t)dir * (CHUNK * BB) + m) * G3 + n0 + tx * 4) = o;
    }
}

// ---------------------------------------------------------------------------
// Tagged staging (proven R6 protocol, unchanged): 8 rows x 512 cols of
// (tag,value) pairs; thread tid takes column tid of every row.  Batched 8x
// dwordx2 in ONE asm block; per-thread retry until every tag matches `exp`.
// Self-validating elements: no flag, no cross-address ordering assumption.
// ---------------------------------------------------------------------------
#define WSTRIDE 516
#define NWCOLS 48
#define P1S 264   // phase-1 part stride (mod 32 == 8)
#define P2S 132   // phase-2 part stride (mod 32 == 4)
#define LDS_FLOATS (NWCOLS * WSTRIDE + 8 * WSTRIDE + 9216 + 640)

__device__ __forceinline__ void stage_tagged(
    const unsigned long long* __restrict__ src,
    float* __restrict__ dst, int tid, unsigned exp)
{
    const unsigned long long* p0 = src + tid;
    const unsigned long long* p1 = src + tid + 512;
    const unsigned long long* p2 = src + tid + 1024;
    const unsigned long long* p3 = src + tid + 1536;
    const unsigned long long* p4 = src + tid + 2048;
    const unsigned long long* p5 = src + tid + 2560;
    const unsigned long long* p6 = src + tid + 3072;
    const unsigned long long* p7 = src + tid + 3584;
    unsigned long long d0, d1, d2, d3, d4, d5, d6, d7;
    for (int spin = 0;; ++spin) {
        asm volatile(
            "global_load_dwordx2 %0, %8, off sc0 sc1\n\t"
            "global_load_dwordx2 %1, %9, off sc0 sc1\n\t"
            "global_load_dwordx2 %2, %10, off sc0 sc1\n\t"
            "global_load_dwordx2 %3, %11, off sc0 sc1\n\t"
            "global_load_dwordx2 %4, %12, off sc0 sc1\n\t"
            "global_load_dwordx2 %5, %13, off sc0 sc1\n\t"
            "global_load_dwordx2 %6, %14, off sc0 sc1\n\t"
            "global_load_dwordx2 %7, %15, off sc0 sc1\n\t"
            "s_waitcnt vmcnt(0)"
            : "=&v"(d0), "=&v"(d1), "=&v"(d2), "=&v"(d3),
              "=&v"(d4), "=&v"(d5), "=&v"(d6), "=&v"(d7)
            : "v"(p0), "v"(p1), "v"(p2), "v"(p3),
              "v"(p4), "v"(p5), "v"(p6), "v"(p7)
            : "memory");
        unsigned bad = (((unsigned)(d0 >> 32)) ^ exp) |
                       (((unsigned)(d1 >> 32)) ^ exp) |
                       (((unsigned)(d2 >> 32)) ^ exp) |
                       (((unsigned)(d3 >> 32)) ^ exp) |
                       (((unsigned)(d4 >> 32)) ^ exp) |
                       (((unsigned)(d5 >> 32)) ^ exp) |
                       (((unsigned)(d6 >> 32)) ^ exp) |
                       (((unsigned)(d7 >> 32)) ^ exp);
        if (bad == 0u || spin > (1 << 18)) break;
        __builtin_amdgcn_s_sleep(1);
    }
    dst[tid]               = __uint_as_float((unsigned)d0);
    dst[WSTRIDE + tid]     = __uint_as_float((unsigned)d1);
    dst[2 * WSTRIDE + tid] = __uint_as_float((unsigned)d2);
    dst[3 * WSTRIDE + tid] = __uint_as_float((unsigned)d3);
    dst[4 * WSTRIDE + tid] = __uint_as_float((unsigned)d4);
    dst[5 * WSTRIDE + tid] = __uint_as_float((unsigned)d5);
    dst[6 * WSTRIDE + tid] = __uint_as_float((unsigned)d6);
    dst[7 * WSTRIDE + tid] = __uint_as_float((unsigned)d7);
}

// ---------------------------------------------------------------------------
// Persistent chunk kernel.  Group = 32 WGs (dir x batch-quad).  Exchange via
// tagged ping-pong (R6, unchanged).  Round-7 compute changes:
//  * Weights hoisted to per-thread REGISTERS (w1[4][4], w2[4][2] float4):
//    staged to LDS once (proven path), each thread reads its 24 float4 once,
//    then Wl is dead.  Removes 24 of 48 ds_read_b128 per thread per STEP
//    (they were loop-invariant across all 64 steps) and their bank conflicts.
//  * rh staged into hp2 (aliases the dead Wl region) instead of reusing hp:
//    the sync between P1-reduce (reads hp/part) and stage-rh (writes hp2)
//    is no longer needed -> 5 syncthreads/step instead of 6.
//  FP arithmetic order per accumulator is unchanged (value-identical).
// ---------------------------------------------------------------------------
__global__ __launch_bounds__(512, 1) void gru_chunk(
    const float* __restrict__ Uf, const float* __restrict__ Ub,
    const float* __restrict__ xgc,
    unsigned long long* __restrict__ hbuf,
    unsigned long long* __restrict__ rhbuf,
    float* __restrict__ out, int c)
{
    extern __shared__ float lds[];
    float* Wl   = lds;                        // 48 cols * 516 (dead after reg load)
    float* hp2  = lds;                        // rh buffer, aliases dead Wl
    float* hp   = Wl + NWCOLS * WSTRIDE;      // 8 rows * 516 (h)
    float* part = hp + 8 * WSTRIDE;           // 9216 (transposed partials)
    float* zloc = part + 9216;                // 8*16
    float* hloc = zloc + 128;                 // 8*16
    float* xg_l = hloc + 128;                 // 384: xz/xr (256) + xh (128)

    const int tid = threadIdx.x;
    const int g   = blockIdx.x >> 5;   // group 0..7
    const int w   = blockIdx.x & 31;   // WG within group
    const int dir = g >> 2;
    const int b0  = (g & 3) * 8;

    const float* U = dir ? Ub : Uf;
    const int j0 = w * 16;             // owned j-range for z, r, cand

    unsigned long long* hg_h[2];
    unsigned long long* hg_rh[2];
    hg_h[0]  = hbuf  + ((size_t)(0 * 2 + dir) * 32 + b0) * 512;
    hg_h[1]  = hbuf  + ((size_t)(1 * 2 + dir) * 32 + b0) * 512;
    hg_rh[0] = rhbuf + ((size_t)(0 * 2 + dir) * 32 + b0) * 512;
    hg_rh[1] = rhbuf + ((size_t)(1 * 2 + dir) * 32 + b0) * 512;

    // ---- stage weights: cc 0..15 = Uz[:,j0+..], 16..31 = Ur, 32..47 = Uh ----
    for (int q = tid; q < 512 * 12; q += 512) {
        int k  = q & 511;
        int jj = q >> 9;                  // 0..11 (float4 spans)
        int gate = jj >> 2;               // 0=z,1=r,2=cand
        int off  = (jj & 3) * 4;
        int n  = gate * 512 + j0 + off;
        int cc = gate * 16 + off;
        float4 v = *(const float4*)(U + (size_t)k * G3 + n);
        float* wc = Wl + (size_t)cc * WSTRIDE + k;
        wc[0]           = v.x;
        wc[WSTRIDE]     = v.y;
        wc[2 * WSTRIDE] = v.z;
        wc[3 * WSTRIDE] = v.w;
    }
    __syncthreads();

    // ---- hoist this thread's weight fragments into registers ----
    float4 w1[4][4];   // P1: col (tid&7)+8*ci, k = (tid>>4)*16 + 4*q ..+3
    float4 w2[4][2];   // P2: col 32+(tid&3)+4*ci, k = (tid>>3)*8 + 4*q ..+3
    {
        const int cs1 = tid & 7, kb1 = (tid >> 4) * 16;
        #pragma unroll
        for (int ci = 0; ci < 4; ++ci)
            #pragma unroll
            for (int q = 0; q < 4; ++q)
                w1[ci][q] = *(const float4*)(Wl + (size_t)(cs1 + 8 * ci) * WSTRIDE
                                             + kb1 + 4 * q);
        const int cs2 = tid & 3, kb2 = (tid >> 3) * 8;
        #pragma unroll
        for (int ci = 0; ci < 4; ++ci)
            #pragma unroll
            for (int q = 0; q < 2; ++q)
                w2[ci][q] = *(const float4*)(Wl + (size_t)(32 + cs2 + 4 * ci) * WSTRIDE
                                             + kb2 + 4 * q);
    }
    __syncthreads();   // Wl dead beyond this point; hp2 may overwrite it

    for (int i = 0; i < CHUNK; ++i) {
        const int t = c * CHUNK + i;
        const int par = t & 1;
        const unsigned tag_next = (unsigned)(t + 1);

        // ---- issue xg prefetch (plain loads; drain with staging vmcnt) ----
        float xgv = 0.f;
        if (tid < 384) {
            size_t off;
            if (tid < 256) {
                off = (((size_t)dir * CHUNK + i) * BB + (b0 + (tid >> 5))) * G3
                    + (size_t)(((tid & 31) >> 4) * 512) + j0 + (tid & 15);
            } else {
                int o2 = tid - 256;
                off = (((size_t)dir * CHUNK + i) * BB + (b0 + (o2 >> 4))) * G3
                    + 1024 + j0 + (o2 & 15);
            }
            xgv = xgc[off];
        }

        // ---- stage h(t-1): parity par^1, expect tag t ----
        stage_tagged(hg_h[par ^ 1], hp, tid, (unsigned)t);
        if (tid < 384) xg_l[tid] = xgv;
        __syncthreads();

        // ---- phase 1 dots: 32 cols (16 z + 16 r) x 8 batches, K=512 ----
        {
            const int cslot = tid & 7;
            const int bslot = (tid >> 3) & 1;
            const int ks    = tid >> 4;      // 0..31
            const int kb    = ks * 16;
            const float* hq = hp + (size_t)(bslot * 4) * WSTRIDE + kb;
            float acc[4][4];
            #pragma unroll
            for (int a = 0; a < 4; ++a)
                #pragma unroll
                for (int b = 0; b < 4; ++b) acc[a][b] = 0.f;
            #pragma unroll
            for (int q = 0; q < 4; ++q) {
                float4 hv[4];
                #pragma unroll
                for (int bi = 0; bi < 4; ++bi)
                    hv[bi] = *(const float4*)(hq + (size_t)bi * WSTRIDE + 4 * q);
                #pragma unroll
                for (int ci = 0; ci < 4; ++ci)
                    #pragma unroll
                    for (int bi = 0; bi < 4; ++bi) {
                        acc[ci][bi] = fmaf(w1[ci][q].x, hv[bi].x, acc[ci][bi]);
                        acc[ci][bi] = fmaf(w1[ci][q].y, hv[bi].y, acc[ci][bi]);
                        acc[ci][bi] = fmaf(w1[ci][q].z, hv[bi].z, acc[ci][bi]);
                        acc[ci][bi] = fmaf(w1[ci][q].w, hv[bi].w, acc[ci][bi]);
                    }
            }
            #pragma unroll
            for (int ci = 0; ci < 4; ++ci)
                #pragma unroll
                for (int bi = 0; bi < 4; ++bi) {
                    int o = (bslot * 4 + bi) * 32 + cslot + 8 * ci;
                    part[(size_t)ks * P1S + o] = acc[ci][bi];
                }
        }
        __syncthreads();

        // ---- phase 1 reduce + epilogue: z->LDS, rh->(tag,val) LLC ----
        if (tid < 256) {
            const int o = tid;
            float s0 = 0.f, s1 = 0.f, s2 = 0.f, s3 = 0.f;
            #pragma unroll
            for (int ks = 0; ks < 32; ks += 4) {
                s0 += part[(size_t)(ks + 0) * P1S + o];
                s1 += part[(size_t)(ks + 1) * P1S + o];
                s2 += part[(size_t)(ks + 2) * P1S + o];
                s3 += part[(size_t)(ks + 3) * P1S + o];
            }
            float s = ((s0 + s1) + (s2 + s3)) + xg_l[o];
            const int b_l = o >> 5, cc = o & 31;
            const int gate = cc >> 4;              // 0=z, 1=r
            const int jl = cc & 15;
            const int j = j0 + jl;
            float gv = hsig(s);
            const float hval = hp[(size_t)b_l * WSTRIDE + j];
            if (gate == 0) {
                zloc[b_l * 16 + jl] = gv;
                hloc[b_l * 16 + jl] = hval;
            } else {
                llc_store_u64(hg_rh[par] + (size_t)b_l * 512 + j,
                              pack_tv(tag_next, gv * hval));
            }
        }
        // no sync needed: stage-rh writes hp2 (dead Wl region), not hp/part

        // ---- stage rh(t): parity par, expect tag t+1 ----
        stage_tagged(hg_rh[par], hp2, tid, tag_next);
        __syncthreads();

        // ---- phase 2 dots: 16 cand cols x 8 batches, K=512 ----
        {
            const int cslot = tid & 3;
            const int bslot = (tid >> 2) & 1;
            const int ks    = tid >> 3;      // 0..63
            const int kb    = ks * 8;
            const float* hq = hp2 + (size_t)(bslot * 4) * WSTRIDE + kb;
            float acc[4][4];
            #pragma unroll
            for (int a = 0; a < 4; ++a)
                #pragma unroll
                for (int b = 0; b < 4; ++b) acc[a][b] = 0.f;
            #pragma unroll
            for (int q = 0; q < 2; ++q) {
                float4 hv[4];
                #pragma unroll
                for (int bi = 0; bi < 4; ++bi)
                    hv[bi] = *(const float4*)(hq + (size_t)bi * WSTRIDE + 4 * q);
                #pragma unroll
                for (int ci = 0; ci < 4; ++ci)
                    #pragma unroll
                    for (int bi = 0; bi < 4; ++bi) {
                        acc[ci][bi] = fmaf(w2[ci][q].x, hv[bi].x, acc[ci][bi]);
                        acc[ci][bi] = fmaf(w2[ci][q].y, hv[bi].y, acc[ci][bi]);
                        acc[ci][bi] = fmaf(w2[ci][q].z, hv[bi].z, acc[ci][bi]);
                        acc[ci][bi] = fmaf(w2[ci][q].w, hv[bi].w, acc[ci][bi]);
                    }
            }
            #pragma unroll
            for (int ci = 0; ci < 4; ++ci)
                #pragma unroll
                for (int bi = 0; bi < 4; ++bi) {
                    int o = (bslot * 4 + bi) * 16 + cslot + 4 * ci;
                    part[(size_t)ks * P2S + o] = acc[ci][bi];
                }
        }
        __syncthreads();

        // ---- phase 2 reduce + h update (z, h_old from LDS) ----
        if (tid < 128) {
            const int o = tid;
            float s0 = 0.f, s1 = 0.f, s2 = 0.f, s3 = 0.f;
            #pragma unroll
            for (int ks = 0; ks < 64; ks += 4) {
                s0 += part[(size_t)(ks + 0) * P2S + o];
                s1 += part[(size_t)(ks + 1) * P2S + o];
                s2 += part[(size_t)(ks + 2) * P2S + o];
                s3 += part[(size_t)(ks + 3) * P2S + o];
            }
            float s = ((s0 + s1) + (s2 + s3)) + xg_l[256 + o];
            const int b_l = o >> 4, jl = o & 15;
            const int j = j0 + jl;
            float cand = tanhf(s);
            float z = zloc[b_l * 16 + jl];
            float h = hloc[b_l * 16 + jl];
            float hn = fmaf(z, h - cand, cand);   // z*h + (1-z)*cand
            llc_store_u64(hg_h[par] + (size_t)b_l * 512 + j,
                          pack_tv(tag_next, hn));
            out[((size_t)(b0 + b_l) * TT + t) * (2 * UU) + (size_t)dir * UU + j] = hn;
        }
        __syncthreads();   // xg_l/zloc/hloc/part reads done before next step
    }
}

extern "C" void kernel_launch(void* const* d_in, const int* in_sizes, int n_in,
                              void* d_out, int out_size, void* d_ws, size_t ws_size,
                              hipStream_t stream) {
    const float* x  = (const float*)d_in[0];
    const float* Wf = (const float*)d_in[1];
    const float* Uf = (const float*)d_in[2];
    const float* bf = (const float*)d_in[3];
    const float* Wb = (const float*)d_in[4];
    const float* Ub = (const float*)d_in[5];
    const float* bb = (const float*)d_in[6];
    float* out = (float*)d_out;

    // ws: tagged ping-pong h[2][2][32][512] u64 (512KB) + rh same (512KB)
    //     + xgc (~25 MB)
    unsigned long long* hbuf  = (unsigned long long*)d_ws;
    unsigned long long* rhbuf = hbuf + (size_t)4 * BB * UU;   // 65536 u64
    float* xgc = (float*)(rhbuf + (size_t)4 * BB * UU);

    hipMemsetAsync(d_ws, 0, (size_t)8 * 4 * BB * UU * 2, stream);  // 1 MiB

    static_assert(LDS_FLOATS * 4 <= 160 * 1024, "LDS overflow");
    hipFuncSetAttribute((const void*)gru_chunk,
                        hipFuncAttributeMaxDynamicSharedMemorySize,
                        LDS_FLOATS * 4);

    for (int c = 0; c < TT / CHUNK; ++c) {
        xg_gemm<<<dim3(24, 16, 2), 256, 0, stream>>>(
            x, Wf, bf, Wb, bb, xgc, c * CHUNK);
        gru_chunk<<<dim3(256), dim3(512), LDS_FLOATS * 4, stream>>>(
            Uf, Ub, xgc, hbuf, rhbuf, out, c);
    }
}